// Round 2
// baseline (512.807 us; speedup 1.0000x reference)
//
#include <hip/hip_runtime.h>
#include <math.h>

#define NB 32
#define NI 2048
#define NO 64
#define NP 16
#define NBLK 32          // grid.x = NI/64
#define EPSF 1e-9f

__device__ __forceinline__ float wave_sum64_shfl(float v) {
#pragma unroll
    for (int off = 32; off > 0; off >>= 1) v += __shfl_xor(v, off);
    return v;
}

// rocPRIM-style wave64 sum via DPP: row_shr 1/2/4/8, row_bcast15 (rows 1,3),
// row_bcast31 (rows 2,3); lane 63 holds the total, broadcast via readlane.
__device__ __forceinline__ float wave_sum64_dpp(float v) {
    v += __int_as_float(__builtin_amdgcn_update_dpp(
        0, __float_as_int(v), 0x111, 0xf, 0xf, false));
    v += __int_as_float(__builtin_amdgcn_update_dpp(
        0, __float_as_int(v), 0x112, 0xf, 0xf, false));
    v += __int_as_float(__builtin_amdgcn_update_dpp(
        0, __float_as_int(v), 0x114, 0xf, 0xf, false));
    v += __int_as_float(__builtin_amdgcn_update_dpp(
        0, __float_as_int(v), 0x118, 0xf, 0xf, false));
    v += __int_as_float(__builtin_amdgcn_update_dpp(
        0, __float_as_int(v), 0x142, 0xa, 0xf, false));
    v += __int_as_float(__builtin_amdgcn_update_dpp(
        0, __float_as_int(v), 0x143, 0xc, 0xf, false));
    return __int_as_float(__builtin_amdgcn_readlane(__float_as_int(v), 63));
}

// ---------------------------------------------------------------------------
// Pass 0: per-block sums of votes over i -> pm[(b*NBLK+bx)*1024 + o*16 + p]
// grid (NBLK, NB), block 256 (4 waves). lane = o.
// ---------------------------------------------------------------------------
__global__ __launch_bounds__(256) void mean_accum_kernel(
        const float* __restrict__ votes, float* __restrict__ pm) {
    const int b    = blockIdx.y;
    const int bx   = blockIdx.x;
    const int wave = threadIdx.x >> 6;
    const int lane = threadIdx.x & 63;  // o

    float s[NP];
#pragma unroll
    for (int p = 0; p < NP; ++p) s[p] = 0.f;

    const float* vbase =
        votes + (((size_t)b * NI + bx * 64 + wave) * NO + lane) * NP;
#pragma unroll 2
    for (int k = 0; k < 16; ++k) {
        const float4* vp =
            reinterpret_cast<const float4*>(vbase + (size_t)k * 4 * NO * NP);
        float4 v0 = vp[0], v1 = vp[1], v2 = vp[2], v3 = vp[3];
        s[0] += v0.x;  s[1] += v0.y;  s[2] += v0.z;  s[3] += v0.w;
        s[4] += v1.x;  s[5] += v1.y;  s[6] += v1.z;  s[7] += v1.w;
        s[8] += v2.x;  s[9] += v2.y;  s[10] += v2.z; s[11] += v2.w;
        s[12] += v3.x; s[13] += v3.y; s[14] += v3.z; s[15] += v3.w;
    }

    __shared__ float red[4][NO * NP];
#pragma unroll
    for (int p = 0; p < NP; ++p) red[wave][lane * NP + p] = s[p];
    __syncthreads();
    float* dst = pm + (size_t)(b * NBLK + bx) * (NO * NP);
    for (int e = threadIdx.x; e < NO * NP; e += 256)
        dst[e] = red[0][e] + red[1][e] + red[2][e] + red[3][e];
}

// ---------------------------------------------------------------------------
// Mu init = l2norm(mean); A init = 1/O.  grid NB, block NO.
// ---------------------------------------------------------------------------
__global__ void mean_final_kernel(const float* __restrict__ pm,
                                  float* __restrict__ Mu, float* __restrict__ A) {
    const int b = blockIdx.x;
    const int o = threadIdx.x;  // 64
    float m[NP];
#pragma unroll
    for (int p = 0; p < NP; ++p) m[p] = 0.f;
    for (int bx = 0; bx < NBLK; ++bx) {
        const float4* q = reinterpret_cast<const float4*>(
            pm + (size_t)(b * NBLK + bx) * (NO * NP) + o * NP);
        float4 q0 = q[0], q1 = q[1], q2 = q[2], q3 = q[3];
        m[0] += q0.x;  m[1] += q0.y;  m[2] += q0.z;  m[3] += q0.w;
        m[4] += q1.x;  m[5] += q1.y;  m[6] += q1.z;  m[7] += q1.w;
        m[8] += q2.x;  m[9] += q2.y;  m[10] += q2.z; m[11] += q2.w;
        m[12] += q3.x; m[13] += q3.y; m[14] += q3.z; m[15] += q3.w;
    }
    float ssq = 0.f;
#pragma unroll
    for (int p = 0; p < NP; ++p) { m[p] *= (1.0f / NI); ssq += m[p] * m[p]; }
    float inv = rsqrtf(fmaxf(ssq, 1e-12f));
#pragma unroll
    for (int p = 0; p < NP; ++p)
        Mu[((size_t)b * NO + o) * NP + p] = m[p] * inv;
    A[b * NO + o] = 1.0f / (float)NO;
}

// ---------------------------------------------------------------------------
// One routing iteration, fused. Partials (no atomics):
//   ppn[(b*NBLK+bx)*1024 + o*16 + p]  (R-weighted vote sums)
//   ppd[(b*NBLK+bx)*128  + o*2 + {0=den,1=rsum}]
// grid (NBLK, NB), block 256. lane = o.
// ---------------------------------------------------------------------------
__global__ __launch_bounds__(256) void iter_accum_kernel(
        const float* __restrict__ votes, const float* __restrict__ act,
        const float* __restrict__ Mu, const float* __restrict__ A,
        float* __restrict__ ppn, float* __restrict__ ppd) {
    const int b    = blockIdx.y;
    const int bx   = blockIdx.x;
    const int wave = threadIdx.x >> 6;
    const int lane = threadIdx.x & 63;  // o

    float mu[NP];
    {
        const float4* mp = reinterpret_cast<const float4*>(
            Mu + ((size_t)b * NO + lane) * NP);
        float4 m0 = mp[0], m1 = mp[1], m2 = mp[2], m3 = mp[3];
        mu[0] = m0.x;  mu[1] = m0.y;  mu[2] = m0.z;  mu[3] = m0.w;
        mu[4] = m1.x;  mu[5] = m1.y;  mu[6] = m1.z;  mu[7] = m1.w;
        mu[8] = m2.x;  mu[9] = m2.y;  mu[10] = m2.z; mu[11] = m2.w;
        mu[12] = m3.x; mu[13] = m3.y; mu[14] = m3.z; mu[15] = m3.w;
    }
    const float Ao   = A[b * NO + lane];
    const float logA = __logf(Ao + EPSF);

    float num[NP];
#pragma unroll
    for (int p = 0; p < NP; ++p) num[p] = 0.f;
    float den = 0.f, rs = 0.f;

    const float* vbase =
        votes + (((size_t)b * NI + bx * 64 + wave) * NO + lane) * NP;
    const float* abase = act + b * NI + bx * 64 + wave;

#pragma unroll 2
    for (int k = 0; k < 16; ++k) {
        const float4* vp =
            reinterpret_cast<const float4*>(vbase + (size_t)k * 4 * NO * NP);
        float4 v0 = vp[0], v1 = vp[1], v2 = vp[2], v3 = vp[3];

        float ssq = v0.x * v0.x + v0.y * v0.y + v0.z * v0.z + v0.w * v0.w
                  + v1.x * v1.x + v1.y * v1.y + v1.z * v1.z + v1.w * v1.w
                  + v2.x * v2.x + v2.y * v2.y + v2.z * v2.z + v2.w * v2.w
                  + v3.x * v3.x + v3.y * v3.y + v3.z * v3.z + v3.w * v3.w;
        float dt  = v0.x * mu[0]  + v0.y * mu[1]  + v0.z * mu[2]  + v0.w * mu[3]
                  + v1.x * mu[4]  + v1.y * mu[5]  + v1.z * mu[6]  + v1.w * mu[7]
                  + v2.x * mu[8]  + v2.y * mu[9]  + v2.z * mu[10] + v2.w * mu[11]
                  + v3.x * mu[12] + v3.y * mu[13] + v3.z * mu[14] + v3.w * mu[15];

        float dn = dt * __builtin_amdgcn_rsqf(fmaxf(ssq, 1e-12f));
        float a  = abase[4 * k];
        // lp in [-22.7, 0] -> exp is safe without max-stabilization;
        // softmax ratio is mathematically identical to the stabilized form.
        float lp = logA - (1.0f - dn * dn) - fabsf(a - Ao);
        float e  = __expf(lp);
        float R  = e * __builtin_amdgcn_rcpf(wave_sum64_dpp(e));

        rs  += R * a;
        den += R;
        num[0]  += R * v0.x; num[1]  += R * v0.y; num[2]  += R * v0.z; num[3]  += R * v0.w;
        num[4]  += R * v1.x; num[5]  += R * v1.y; num[6]  += R * v1.z; num[7]  += R * v1.w;
        num[8]  += R * v2.x; num[9]  += R * v2.y; num[10] += R * v2.z; num[11] += R * v2.w;
        num[12] += R * v3.x; num[13] += R * v3.y; num[14] += R * v3.z; num[15] += R * v3.w;
    }

    // block-level reduction of 4 waves (LDS), then plain stores
    __shared__ float red[4][NO * 18];
    float* myred = &red[wave][lane * 18];
#pragma unroll
    for (int p = 0; p < NP; ++p) myred[p] = num[p];
    myred[16] = den;
    myred[17] = rs;
    __syncthreads();
    {
        float* dn_ = ppn + (size_t)(b * NBLK + bx) * (NO * NP);
        for (int e = threadIdx.x; e < NO * NP; e += 256) {
            int o = e >> 4, p = e & 15;
            dn_[e] = red[0][o * 18 + p] + red[1][o * 18 + p]
                   + red[2][o * 18 + p] + red[3][o * 18 + p];
        }
        float* dd_ = ppd + (size_t)(b * NBLK + bx) * (NO * 2);
        for (int e = threadIdx.x; e < NO * 2; e += 256) {
            int o = e >> 1, k = 16 + (e & 1);
            dd_[e] = red[0][o * 18 + k] + red[1][o * 18 + k]
                   + red[2][o * 18 + k] + red[3][o * 18 + k];
        }
    }
}

// ---------------------------------------------------------------------------
// A_h and Mu_h from partials.  grid NB, block NO (1 wave).
// ---------------------------------------------------------------------------
__global__ void finalize_kernel(const float* __restrict__ ppn,
                                const float* __restrict__ ppd,
                                float* __restrict__ Mu_out,
                                float* __restrict__ A_out) {
    const int b = blockIdx.x;
    const int o = threadIdx.x;  // 64
    float num[NP];
#pragma unroll
    for (int p = 0; p < NP; ++p) num[p] = 0.f;
    float den = 0.f, rs = 0.f;
    for (int bx = 0; bx < NBLK; ++bx) {
        const float4* q = reinterpret_cast<const float4*>(
            ppn + (size_t)(b * NBLK + bx) * (NO * NP) + o * NP);
        float4 q0 = q[0], q1 = q[1], q2 = q[2], q3 = q[3];
        num[0] += q0.x;  num[1] += q0.y;  num[2] += q0.z;  num[3] += q0.w;
        num[4] += q1.x;  num[5] += q1.y;  num[6] += q1.z;  num[7] += q1.w;
        num[8] += q2.x;  num[9] += q2.y;  num[10] += q2.z; num[11] += q2.w;
        num[12] += q3.x; num[13] += q3.y; num[14] += q3.z; num[15] += q3.w;
        const float2* d = reinterpret_cast<const float2*>(
            ppd + (size_t)(b * NBLK + bx) * (NO * 2) + o * 2);
        float2 dv = d[0];
        den += dv.x;
        rs  += dv.y;
    }
    float tot = wave_sum64_shfl(rs);
    float Anew = rs / (tot + EPSF);
    Anew = fminf(fmaxf(Anew, EPSF), 1.0f - EPSF);
    A_out[b * NO + o] = Anew;

    float inv_dn = 1.0f / (den + EPSF);
    float ssq = 0.f;
#pragma unroll
    for (int p = 0; p < NP; ++p) { num[p] *= inv_dn; ssq += num[p] * num[p]; }
    float inv = rsqrtf(fmaxf(ssq, 1e-12f));
#pragma unroll
    for (int p = 0; p < NP; ++p)
        Mu_out[((size_t)b * NO + o) * NP + p] = num[p] * inv;
}

// ---------------------------------------------------------------------------
extern "C" void kernel_launch(void* const* d_in, const int* in_sizes, int n_in,
                              void* d_out, int out_size, void* d_ws, size_t ws_size,
                              hipStream_t stream) {
    const float* votes = (const float*)d_in[0];
    const float* act   = (const float*)d_in[1];

    float* Mu_out = (float*)d_out;                 // NB*NO*NP = 32768
    float* A_out  = (float*)d_out + NB * NO * NP;  // NB*NO    = 2048

    float* ws  = (float*)d_ws;
    float* ppn = ws;                               // NB*NBLK*1024 = 1,048,576
    float* ppd = ws + NB * NBLK * 1024;            // NB*NBLK*128  =   131,072
    float* Mu  = ppd + NB * NBLK * 128;            // 32768
    float* A   = Mu + NB * NO * NP;                // 2048

    dim3 grid(NBLK, NB);
    dim3 blk(256);

    // Pass 0: mean -> Mu init, A init (no zero-init needed: plain stores)
    mean_accum_kernel<<<grid, blk, 0, stream>>>(votes, ppn);
    mean_final_kernel<<<NB, NO, 0, stream>>>(ppn, Mu, A);

    // 3 routing iterations
    for (int it = 0; it < 3; ++it) {
        iter_accum_kernel<<<grid, blk, 0, stream>>>(votes, act, Mu, A, ppn, ppd);
        float* mo = (it == 2) ? Mu_out : Mu;
        float* ao = (it == 2) ? A_out  : A;
        finalize_kernel<<<NB, NO, 0, stream>>>(ppn, ppd, mo, ao);
    }
}

// Round 5
// 511.761 us; speedup vs baseline: 1.0020x; 1.0020x over previous
//
#include <hip/hip_runtime.h>
#include <math.h>

#define NB 32
#define NI 2048
#define NO 64
#define NP 16
#define IBLK 32
#define NXB (NI / IBLK)   // 64 blocks along i
#define EPSF 1e-9f

__device__ __forceinline__ float wave_sum64_shfl(float v) {
#pragma unroll
    for (int off = 32; off > 0; off >>= 1) v += __shfl_xor(v, off);
    return v;
}

template <int CTRL, int RM, int BM>
__device__ __forceinline__ float dppadd(float v) {
    return v + __int_as_float(__builtin_amdgcn_update_dpp(
        0, __float_as_int(v), CTRL, RM, BM, false));
}

// full-wave64 sum (rocPRIM pattern), total broadcast from lane 63
__device__ __forceinline__ float wave_sum64_dpp(float v) {
    v = dppadd<0x111, 0xf, 0xf>(v);  // row_shr:1
    v = dppadd<0x112, 0xf, 0xf>(v);  // row_shr:2
    v = dppadd<0x114, 0xf, 0xf>(v);  // row_shr:4
    v = dppadd<0x118, 0xf, 0xf>(v);  // row_shr:8
    v = dppadd<0x142, 0xa, 0xf>(v);  // row_bcast:15
    v = dppadd<0x143, 0xc, 0xf>(v);  // row_bcast:31
    return __int_as_float(__builtin_amdgcn_readlane(__float_as_int(v), 63));
}

// sum across the 4 lanes of a quad; every lane of the quad gets the total
__device__ __forceinline__ float quad_sum4(float v) {
    v = dppadd<0xB1, 0xf, 0xf>(v);  // quad_perm [1,0,3,2]  (xor 1)
    v = dppadd<0x4E, 0xf, 0xf>(v);  // quad_perm [2,3,0,1]  (xor 2)
    return v;
}

// ---------------------------------------------------------------------------
// Pass 0: per-block sums over i -> ppn[(b*NXB+bx)*1024 + o*16+p]
// Lane-contiguous: lane l, instr j covers flat (o,p) = j*256 + l*4 .. +3.
// grid (NXB, NB), block 256 (4 waves); wave handles IBLK/4 = 8 consecutive i.
// ---------------------------------------------------------------------------
__global__ __launch_bounds__(256) void mean_accum_kernel(
        const float* __restrict__ votes, float* __restrict__ ppn) {
    const int b  = blockIdx.y;
    const int bx = blockIdx.x;
    const int w  = threadIdx.x >> 6;
    const int l  = threadIdx.x & 63;

    const float4* vb = reinterpret_cast<const float4*>(votes)
                     + (((size_t)b * NI + bx * IBLK + w * (IBLK / 4)) << 8) + l;

    float s[16];
#pragma unroll
    for (int p = 0; p < 16; ++p) s[p] = 0.f;

#pragma unroll 2
    for (int k = 0; k < IBLK / 4; ++k) {
        const float4* pk = vb + ((size_t)k << 8);
        float4 v0 = pk[0], v1 = pk[64], v2 = pk[128], v3 = pk[192];
        s[0]  += v0.x; s[1]  += v0.y; s[2]  += v0.z; s[3]  += v0.w;
        s[4]  += v1.x; s[5]  += v1.y; s[6]  += v1.z; s[7]  += v1.w;
        s[8]  += v2.x; s[9]  += v2.y; s[10] += v2.z; s[11] += v2.w;
        s[12] += v3.x; s[13] += v3.y; s[14] += v3.z; s[15] += v3.w;
    }

    __shared__ float red[4][NO * NP];
    float4* r4 = reinterpret_cast<float4*>(red[w]);
    r4[0 * 64 + l] = make_float4(s[0], s[1], s[2], s[3]);
    r4[1 * 64 + l] = make_float4(s[4], s[5], s[6], s[7]);
    r4[2 * 64 + l] = make_float4(s[8], s[9], s[10], s[11]);
    r4[3 * 64 + l] = make_float4(s[12], s[13], s[14], s[15]);
    __syncthreads();
    float* dst = ppn + (size_t)(b * NXB + bx) * (NO * NP);
    for (int e = threadIdx.x; e < NO * NP; e += 256)
        dst[e] = red[0][e] + red[1][e] + red[2][e] + red[3][e];
}

// ---------------------------------------------------------------------------
// Mu init = l2norm(mean); A init = 1/O.  grid NB, block 256.
// ---------------------------------------------------------------------------
__global__ __launch_bounds__(256) void mean_final_kernel(
        const float* __restrict__ ppn, float* __restrict__ Mu,
        float* __restrict__ A) {
    const int b = blockIdx.x;
    const int w = threadIdx.x >> 6;
    const int l = threadIdx.x & 63;  // o

    float m[16];
#pragma unroll
    for (int p = 0; p < 16; ++p) m[p] = 0.f;
    for (int bx = w; bx < NXB; bx += 4) {
        const float4* q = reinterpret_cast<const float4*>(
            ppn + (size_t)(b * NXB + bx) * (NO * NP) + l * NP);
        float4 q0 = q[0], q1 = q[1], q2 = q[2], q3 = q[3];
        m[0]  += q0.x; m[1]  += q0.y; m[2]  += q0.z; m[3]  += q0.w;
        m[4]  += q1.x; m[5]  += q1.y; m[6]  += q1.z; m[7]  += q1.w;
        m[8]  += q2.x; m[9]  += q2.y; m[10] += q2.z; m[11] += q2.w;
        m[12] += q3.x; m[13] += q3.y; m[14] += q3.z; m[15] += q3.w;
    }
    __shared__ float red[4][NO * 17];
#pragma unroll
    for (int p = 0; p < 16; ++p) red[w][l * 17 + p] = m[p];
    __syncthreads();
    if (w == 0) {
        float mm[16], ssq = 0.f;
#pragma unroll
        for (int p = 0; p < 16; ++p) {
            mm[p] = (red[0][l * 17 + p] + red[1][l * 17 + p]
                   + red[2][l * 17 + p] + red[3][l * 17 + p]) * (1.0f / NI);
            ssq += mm[p] * mm[p];
        }
        float inv = rsqrtf(fmaxf(ssq, 1e-12f));
        float4* mo = reinterpret_cast<float4*>(Mu + ((size_t)b * NO + l) * NP);
        mo[0] = make_float4(mm[0] * inv, mm[1] * inv, mm[2] * inv, mm[3] * inv);
        mo[1] = make_float4(mm[4] * inv, mm[5] * inv, mm[6] * inv, mm[7] * inv);
        mo[2] = make_float4(mm[8] * inv, mm[9] * inv, mm[10] * inv, mm[11] * inv);
        mo[3] = make_float4(mm[12] * inv, mm[13] * inv, mm[14] * inv, mm[15] * inv);
        A[b * NO + l] = 1.0f / (float)NO;
    }
}

// ---------------------------------------------------------------------------
// One routing iteration, fused, lane-contiguous loads.
// Lane l handles o_j = 16j + (l>>2), p = 4*(l&3)..+3, j=0..3.
// grid (NXB, NB), block 256.
// ---------------------------------------------------------------------------
__global__ __launch_bounds__(256) void iter_accum_kernel(
        const float* __restrict__ votes, const float* __restrict__ act,
        const float* __restrict__ Mu, const float* __restrict__ A,
        float* __restrict__ ppn, float* __restrict__ ppd) {
    const int b  = blockIdx.y;
    const int bx = blockIdx.x;
    const int w  = threadIdx.x >> 6;
    const int l  = threadIdx.x & 63;
    const int qd = l >> 2;   // 0..15
    const int pc = l & 3;    // p-chunk

    float mu[16], Ao[4], lA[4];
#pragma unroll
    for (int j = 0; j < 4; ++j) {
        int o = 16 * j + qd;
        float4 mv = reinterpret_cast<const float4*>(
            Mu + ((size_t)b * NO + o) * NP)[pc];
        mu[4 * j + 0] = mv.x; mu[4 * j + 1] = mv.y;
        mu[4 * j + 2] = mv.z; mu[4 * j + 3] = mv.w;
        Ao[j] = A[b * NO + o];
        lA[j] = __logf(Ao[j] + EPSF);
    }

    float acc[16], den[4], rs[4];
#pragma unroll
    for (int p = 0; p < 16; ++p) acc[p] = 0.f;
#pragma unroll
    for (int j = 0; j < 4; ++j) { den[j] = 0.f; rs[j] = 0.f; }

    const int i0 = bx * IBLK + w * (IBLK / 4);
    const float4* vb = reinterpret_cast<const float4*>(votes)
                     + (((size_t)b * NI + i0) << 8) + l;
    const float* ab = act + b * NI + i0;

#pragma unroll 2
    for (int k = 0; k < IBLK / 4; ++k) {
        const float4* pk = vb + ((size_t)k << 8);
        float4 v0 = pk[0], v1 = pk[64], v2 = pk[128], v3 = pk[192];
        float a = ab[k];

        float dt0 = v0.x * mu[0]  + v0.y * mu[1]  + v0.z * mu[2]  + v0.w * mu[3];
        float dt1 = v1.x * mu[4]  + v1.y * mu[5]  + v1.z * mu[6]  + v1.w * mu[7];
        float dt2 = v2.x * mu[8]  + v2.y * mu[9]  + v2.z * mu[10] + v2.w * mu[11];
        float dt3 = v3.x * mu[12] + v3.y * mu[13] + v3.z * mu[14] + v3.w * mu[15];
        float sq0 = v0.x * v0.x + v0.y * v0.y + v0.z * v0.z + v0.w * v0.w;
        float sq1 = v1.x * v1.x + v1.y * v1.y + v1.z * v1.z + v1.w * v1.w;
        float sq2 = v2.x * v2.x + v2.y * v2.y + v2.z * v2.z + v2.w * v2.w;
        float sq3 = v3.x * v3.x + v3.y * v3.y + v3.z * v3.z + v3.w * v3.w;

        dt0 = quad_sum4(dt0); sq0 = quad_sum4(sq0);
        dt1 = quad_sum4(dt1); sq1 = quad_sum4(sq1);
        dt2 = quad_sum4(dt2); sq2 = quad_sum4(sq2);
        dt3 = quad_sum4(dt3); sq3 = quad_sum4(sq3);

        // lp in [-22.7, 0] -> exp safe without max-stabilization
        float e0 = __expf(lA[0] - (1.0f - dt0 * dt0 * __builtin_amdgcn_rcpf(fmaxf(sq0, 1e-12f))) - fabsf(a - Ao[0]));
        float e1 = __expf(lA[1] - (1.0f - dt1 * dt1 * __builtin_amdgcn_rcpf(fmaxf(sq1, 1e-12f))) - fabsf(a - Ao[1]));
        float e2 = __expf(lA[2] - (1.0f - dt2 * dt2 * __builtin_amdgcn_rcpf(fmaxf(sq2, 1e-12f))) - fabsf(a - Ao[2]));
        float e3 = __expf(lA[3] - (1.0f - dt3 * dt3 * __builtin_amdgcn_rcpf(fmaxf(sq3, 1e-12f))) - fabsf(a - Ao[3]));

        // each o appears in 4 lanes of its quad -> wave total = 4*S
        float S  = wave_sum64_dpp(e0 + e1 + e2 + e3) * 0.25f;
        float ri = __builtin_amdgcn_rcpf(S);

        float R0 = e0 * ri, R1 = e1 * ri, R2 = e2 * ri, R3 = e3 * ri;
        den[0] += R0; den[1] += R1; den[2] += R2; den[3] += R3;
        rs[0] += R0 * a; rs[1] += R1 * a; rs[2] += R2 * a; rs[3] += R3 * a;
        acc[0]  += R0 * v0.x; acc[1]  += R0 * v0.y; acc[2]  += R0 * v0.z; acc[3]  += R0 * v0.w;
        acc[4]  += R1 * v1.x; acc[5]  += R1 * v1.y; acc[6]  += R1 * v1.z; acc[7]  += R1 * v1.w;
        acc[8]  += R2 * v2.x; acc[9]  += R2 * v2.y; acc[10] += R2 * v2.z; acc[11] += R2 * v2.w;
        acc[12] += R3 * v3.x; acc[13] += R3 * v3.y; acc[14] += R3 * v3.z; acc[15] += R3 * v3.w;
    }

    __shared__ float redn[4][NO * NP];
    __shared__ float redd[4][NO * 2];
    float4* r4 = reinterpret_cast<float4*>(redn[w]);
    r4[0 * 64 + l] = make_float4(acc[0], acc[1], acc[2], acc[3]);
    r4[1 * 64 + l] = make_float4(acc[4], acc[5], acc[6], acc[7]);
    r4[2 * 64 + l] = make_float4(acc[8], acc[9], acc[10], acc[11]);
    r4[3 * 64 + l] = make_float4(acc[12], acc[13], acc[14], acc[15]);
    if (pc == 0) {
#pragma unroll
        for (int j = 0; j < 4; ++j) {
            int o = 16 * j + qd;
            redd[w][o * 2 + 0] = den[j];
            redd[w][o * 2 + 1] = rs[j];
        }
    }
    __syncthreads();
    float* dn_ = ppn + (size_t)(b * NXB + bx) * (NO * NP);
    for (int e = threadIdx.x; e < NO * NP; e += 256)
        dn_[e] = redn[0][e] + redn[1][e] + redn[2][e] + redn[3][e];
    float* dd_ = ppd + (size_t)(b * NXB + bx) * (NO * 2);
    for (int e = threadIdx.x; e < NO * 2; e += 256)
        dd_[e] = redd[0][e] + redd[1][e] + redd[2][e] + redd[3][e];
}

// ---------------------------------------------------------------------------
// A_h and Mu_h from partials.  grid NB, block 256.
// ---------------------------------------------------------------------------
__global__ __launch_bounds__(256) void finalize_kernel(
        const float* __restrict__ ppn, const float* __restrict__ ppd,
        float* __restrict__ Mu_out, float* __restrict__ A_out) {
    const int b = blockIdx.x;
    const int w = threadIdx.x >> 6;
    const int l = threadIdx.x & 63;  // o

    float m[16], den = 0.f, rs = 0.f;
#pragma unroll
    for (int p = 0; p < 16; ++p) m[p] = 0.f;
    for (int bx = w; bx < NXB; bx += 4) {
        const float4* q = reinterpret_cast<const float4*>(
            ppn + (size_t)(b * NXB + bx) * (NO * NP) + l * NP);
        float4 q0 = q[0], q1 = q[1], q2 = q[2], q3 = q[3];
        m[0]  += q0.x; m[1]  += q0.y; m[2]  += q0.z; m[3]  += q0.w;
        m[4]  += q1.x; m[5]  += q1.y; m[6]  += q1.z; m[7]  += q1.w;
        m[8]  += q2.x; m[9]  += q2.y; m[10] += q2.z; m[11] += q2.w;
        m[12] += q3.x; m[13] += q3.y; m[14] += q3.z; m[15] += q3.w;
        float2 d = reinterpret_cast<const float2*>(
            ppd + (size_t)(b * NXB + bx) * (NO * 2))[l];
        den += d.x; rs += d.y;
    }
    __shared__ float red[4][NO * 17];
    __shared__ float redd2[4][NO * 2];
#pragma unroll
    for (int p = 0; p < 16; ++p) red[w][l * 17 + p] = m[p];
    redd2[w][l * 2 + 0] = den;
    redd2[w][l * 2 + 1] = rs;
    __syncthreads();
    if (w == 0) {
        den = redd2[0][l * 2] + redd2[1][l * 2] + redd2[2][l * 2] + redd2[3][l * 2];
        rs  = redd2[0][l * 2 + 1] + redd2[1][l * 2 + 1]
            + redd2[2][l * 2 + 1] + redd2[3][l * 2 + 1];
        float tot  = wave_sum64_shfl(rs);
        float Anew = fminf(fmaxf(rs / (tot + EPSF), EPSF), 1.0f - EPSF);
        A_out[b * NO + l] = Anew;

        float invd = 1.0f / (den + EPSF);
        float mm[16], ssq = 0.f;
#pragma unroll
        for (int p = 0; p < 16; ++p) {
            mm[p] = (red[0][l * 17 + p] + red[1][l * 17 + p]
                   + red[2][l * 17 + p] + red[3][l * 17 + p]) * invd;
            ssq += mm[p] * mm[p];
        }
        float inv = rsqrtf(fmaxf(ssq, 1e-12f));
        float4* mo = reinterpret_cast<float4*>(Mu_out + ((size_t)b * NO + l) * NP);
        mo[0] = make_float4(mm[0] * inv, mm[1] * inv, mm[2] * inv, mm[3] * inv);
        mo[1] = make_float4(mm[4] * inv, mm[5] * inv, mm[6] * inv, mm[7] * inv);
        mo[2] = make_float4(mm[8] * inv, mm[9] * inv, mm[10] * inv, mm[11] * inv);
        mo[3] = make_float4(mm[12] * inv, mm[13] * inv, mm[14] * inv, mm[15] * inv);
    }
}

// ---------------------------------------------------------------------------
extern "C" void kernel_launch(void* const* d_in, const int* in_sizes, int n_in,
                              void* d_out, int out_size, void* d_ws, size_t ws_size,
                              hipStream_t stream) {
    const float* votes = (const float*)d_in[0];
    const float* act   = (const float*)d_in[1];

    float* Mu_out = (float*)d_out;                 // NB*NO*NP
    float* A_out  = (float*)d_out + NB * NO * NP;  // NB*NO

    float* ws  = (float*)d_ws;
    float* ppn = ws;                                   // NB*NXB*1024 floats
    float* ppd = ws + (size_t)NB * NXB * (NO * NP);    // NB*NXB*128 floats
    float* Mu  = ppd + (size_t)NB * NXB * (NO * 2);
    float* A   = Mu + NB * NO * NP;

    dim3 grid(NXB, NB);
    dim3 blk(256);

    mean_accum_kernel<<<grid, blk, 0, stream>>>(votes, ppn);
    mean_final_kernel<<<NB, blk, 0, stream>>>(ppn, Mu, A);

    for (int it = 0; it < 3; ++it) {
        iter_accum_kernel<<<grid, blk, 0, stream>>>(votes, act, Mu, A, ppn, ppd);
        float* mo = (it == 2) ? Mu_out : Mu;
        float* ao = (it == 2) ? A_out  : A;
        finalize_kernel<<<NB, blk, 0, stream>>>(ppn, ppd, mo, ao);
    }
}